// Round 1
// baseline (2024.745 us; speedup 1.0000x reference)
//
#include <hip/hip_runtime.h>
#include <stdint.h>
#include <stddef.h>

// BitLinear: out[i,j] = (gamma_i * alpha / 127) * sum_k q[i,k] * t[j,k]
//   q = rint(x / gamma * 127)  in [-127,127]  (exact in bf16)
//   t = clip(rint(w / alpha), -1, 1)          (exact in bf16)
// Integer dot products are exact in bf16 MFMA with fp32 accum (< 2^24).

#define FAN_IN  4096
#define FAN_OUT 16384
#define NROWS   8192                       // BATCH*SEQ = 4*2048
#define NW_ELEM (FAN_OUT * FAN_IN)         // 67108864

typedef __bf16 bf16_t;
typedef __bf16 bf16x4 __attribute__((ext_vector_type(4)));
typedef __bf16 bf16x8 __attribute__((ext_vector_type(8)));
typedef float  f32x4  __attribute__((ext_vector_type(4)));

// ---------------- K1: sum of |w| (fp64) ----------------
__global__ __launch_bounds__(256) void k_abs_sum(const float* __restrict__ w,
                                                 double* __restrict__ sum) {
  const float4* w4 = (const float4*)w;
  const int n4 = NW_ELEM / 4;
  int tid = blockIdx.x * 256 + threadIdx.x;
  int stride = gridDim.x * 256;
  double s = 0.0;
  for (int i = tid; i < n4; i += stride) {
    float4 v = w4[i];
    s += (double)fabsf(v.x);
    s += (double)fabsf(v.y);
    s += (double)fabsf(v.z);
    s += (double)fabsf(v.w);
  }
  __shared__ double sd[256];
  sd[threadIdx.x] = s;
  __syncthreads();
  for (int off = 128; off > 0; off >>= 1) {
    if (threadIdx.x < off) sd[threadIdx.x] += sd[threadIdx.x + off];
    __syncthreads();
  }
  if (threadIdx.x == 0) atomicAdd(sum, sd[0]);
}

// ---------------- K2: ternarize weights -> bf16 ----------------
__global__ __launch_bounds__(256) void k_quant_w(const float* __restrict__ w,
                                                 bf16_t* __restrict__ t,
                                                 const double* __restrict__ sum) {
  // fp32 division to match numpy's boundary rounding; rintf = round-half-even
  const float alpha = (float)(*sum / (double)NW_ELEM + 1e-8);
  const float4* w4 = (const float4*)w;
  bf16x4* t4 = (bf16x4*)t;
  const int n4 = NW_ELEM / 4;
  int tid = blockIdx.x * 256 + threadIdx.x;
  int stride = gridDim.x * 256;
  for (int i = tid; i < n4; i += stride) {
    float4 v = w4[i];
    float a0 = fminf(fmaxf(rintf(v.x / alpha), -1.0f), 1.0f);
    float a1 = fminf(fmaxf(rintf(v.y / alpha), -1.0f), 1.0f);
    float a2 = fminf(fmaxf(rintf(v.z / alpha), -1.0f), 1.0f);
    float a3 = fminf(fmaxf(rintf(v.w / alpha), -1.0f), 1.0f);
    bf16x4 o = { (bf16_t)a0, (bf16_t)a1, (bf16_t)a2, (bf16_t)a3 };
    t4[i] = o;
  }
}

// ---------------- K3: per-row absmax + int8-code quant of x -> bf16 ----------------
__global__ __launch_bounds__(256) void k_quant_x(const float* __restrict__ x,
                                                 bf16_t* __restrict__ q,
                                                 float* __restrict__ gamma) {
  const int row = blockIdx.x;
  const float4* xr = (const float4*)(x + (size_t)row * FAN_IN);
  float4 v[4];
  float m = 0.0f;
#pragma unroll
  for (int i = 0; i < 4; ++i) {
    v[i] = xr[threadIdx.x + i * 256];
    m = fmaxf(m, fmaxf(fmaxf(fabsf(v[i].x), fabsf(v[i].y)),
                       fmaxf(fabsf(v[i].z), fabsf(v[i].w))));
  }
#pragma unroll
  for (int off = 32; off > 0; off >>= 1) m = fmaxf(m, __shfl_down(m, off));
  __shared__ float sm[4];
  if ((threadIdx.x & 63) == 0) sm[threadIdx.x >> 6] = m;
  __syncthreads();
  float g = fmaxf(fmaxf(sm[0], sm[1]), fmaxf(sm[2], sm[3]));
  g = fmaxf(g, 1e-8f);
  const float sc = 127.0f / g;
  bf16x4* qr = (bf16x4*)(q + (size_t)row * FAN_IN);
#pragma unroll
  for (int i = 0; i < 4; ++i) {
    bf16x4 o = { (bf16_t)rintf(v[i].x * sc), (bf16_t)rintf(v[i].y * sc),
                 (bf16_t)rintf(v[i].z * sc), (bf16_t)rintf(v[i].w * sc) };
    qr[threadIdx.x + i * 256] = o;
  }
  if (threadIdx.x == 0) gamma[row] = g;
}

// ---------------- K4: GEMM  C[i,j] = sum_k q[i,k]*t[j,k], scaled epilogue ----------
// m97 structure: 128x128 tile, BK=64, 4 waves (2x2), mfma_f32_16x16x32_bf16,
// global_load_lds width=16. LDS layout is chunked (16B = 8 bf16 per chunk) with
// XOR swizzle applied on the GLOBAL source address (LDS dest must stay
// wave-uniform-base + lane*16): LDS chunk (m, cc) holds global chunk cc^(m&7).
// This spreads the ds_read_b128 column reads across all 32 banks.
__global__ __launch_bounds__(256) void k_gemm(const bf16_t* __restrict__ Q,
                                              const bf16_t* __restrict__ T,
                                              const float* __restrict__ gamma,
                                              const double* __restrict__ sum,
                                              float* __restrict__ out) {
  __shared__ __align__(16) bf16_t As[128 * 64];
  __shared__ __align__(16) bf16_t Bs[128 * 64];

  // block swizzle: 16 row-tiles fastest -> concurrent window reuses B slabs in L2/L3
  const int bid = blockIdx.x;
  const int group = bid >> 11;        // / (16*128)
  const int rem = bid & 2047;
  const int im = group * 16 + (rem & 15);   // [0,64)
  const int jn = rem >> 4;                  // [0,128)

  const int tid = threadIdx.x;
  const int lane = tid & 63;
  const int wave = tid >> 6;
  const int wm = wave & 1;
  const int wn = wave >> 1;

  const size_t i0 = (size_t)im * 128;
  const size_t j0 = (size_t)jn * 128;

  f32x4 acc[4][4] = {};

  // staging: 4 issues per matrix; chunk ci = s*256 + tid; row m = ci>>3,
  // in-row chunk cc = ci&7 holds global chunk cg = cc ^ (m&7)
  const bf16_t* gA[4];
  const bf16_t* gB[4];
#pragma unroll
  for (int s = 0; s < 4; ++s) {
    int ci = s * 256 + tid;
    int m = ci >> 3;
    int cg = (ci & 7) ^ (m & 7);
    gA[s] = Q + ((i0 + m) * FAN_IN + cg * 8);
    gB[s] = T + ((j0 + m) * FAN_IN + cg * 8);
  }
  const int ldsbase = (tid & ~63) * 8;  // wave-uniform base (elements), +lane*16B by HW

  for (int kt = 0; kt < FAN_IN / 64; ++kt) {
    __syncthreads();
#pragma unroll
    for (int s = 0; s < 4; ++s) {
      __builtin_amdgcn_global_load_lds(
          (const __attribute__((address_space(1))) uint32_t*)gA[s],
          (__attribute__((address_space(3))) uint32_t*)(As + s * 2048 + ldsbase),
          16, 0, 0);
      gA[s] += 64;
    }
#pragma unroll
    for (int s = 0; s < 4; ++s) {
      __builtin_amdgcn_global_load_lds(
          (const __attribute__((address_space(1))) uint32_t*)gB[s],
          (__attribute__((address_space(3))) uint32_t*)(Bs + s * 2048 + ldsbase),
          16, 0, 0);
      gB[s] += 64;
    }
    __syncthreads();
#pragma unroll
    for (int kk = 0; kk < 2; ++kk) {
      const int crow = kk * 4 + (lane >> 4);  // k-chunk index requested
      bf16x8 a[4], b[4];
#pragma unroll
      for (int mi = 0; mi < 4; ++mi) {
        int m = wm * 64 + mi * 16 + (lane & 15);
        a[mi] = *(const bf16x8*)(As + (m * 8 + (crow ^ (m & 7))) * 8);
      }
#pragma unroll
      for (int ni = 0; ni < 4; ++ni) {
        int n = wn * 64 + ni * 16 + (lane & 15);
        b[ni] = *(const bf16x8*)(Bs + (n * 8 + (crow ^ (n & 7))) * 8);
      }
#pragma unroll
      for (int mi = 0; mi < 4; ++mi)
#pragma unroll
        for (int ni = 0; ni < 4; ++ni)
          acc[mi][ni] = __builtin_amdgcn_mfma_f32_16x16x32_bf16(
              a[mi], b[ni], acc[mi][ni], 0, 0, 0);
    }
  }

  // epilogue: C/D layout col=lane&15, row=(lane>>4)*4+r  (verified m89/m91)
  const float alpha = (float)(*sum / (double)NW_ELEM + 1e-8);
  const int lr = lane >> 4;
  const int lc = lane & 15;
#pragma unroll
  for (int mi = 0; mi < 4; ++mi) {
    size_t gi = i0 + wm * 64 + mi * 16 + lr * 4;
#pragma unroll
    for (int r = 0; r < 4; ++r) {
      const float scl = gamma[gi + r] * alpha * (1.0f / 127.0f);
      float* orow = out + (gi + r) * (size_t)FAN_OUT;
#pragma unroll
      for (int ni = 0; ni < 4; ++ni) {
        size_t gj = j0 + wn * 64 + ni * 16 + lc;
        orow[gj] = acc[mi][ni][r] * scl;
      }
    }
  }
}

// ---------------- launch ----------------
extern "C" void kernel_launch(void* const* d_in, const int* in_sizes, int n_in,
                              void* d_out, int out_size, void* d_ws, size_t ws_size,
                              hipStream_t stream) {
  const float* x = (const float*)d_in[0];
  const float* w = (const float*)d_in[1];
  float* out = (float*)d_out;
  char* ws = (char*)d_ws;

  // ws layout: [0,8) fp64 sum | [1024, 33792) gamma (8192 f32)
  //            [1 MiB, +64 MiB) q bf16 | then t bf16 (128 MiB). Total ~193 MiB.
  double* sum = (double*)ws;
  float* gamma = (float*)(ws + 1024);
  bf16_t* q = (bf16_t*)(ws + (1u << 20));
  bf16_t* t = (bf16_t*)(ws + (size_t)(1u << 20) + (size_t)NROWS * FAN_IN * 2);

  hipMemsetAsync(sum, 0, sizeof(double), stream);
  k_abs_sum<<<1024, 256, 0, stream>>>(w, sum);
  k_quant_w<<<4096, 256, 0, stream>>>(w, t, sum);
  k_quant_x<<<NROWS, 256, 0, stream>>>(x, q, gamma);
  k_gemm<<<8192, 256, 0, stream>>>(q, t, gamma, sum, out);
}